// Round 6
// baseline (303.248 us; speedup 1.0000x reference)
//
#include <hip/hip_runtime.h>
#include <hip/hip_bf16.h>

#define NROW 8192
#define NDIM 256
#define INV_T (1.0f / 0.07f)
#define K_BOT 819      // first selected descending rank
#define K_TOP 4095     // one past last selected rank
#define N_SEL 3276
#define N_UNSEL 4916   // 8192 - N_SEL (includes diagonal at -10)

typedef unsigned int u32;
typedef unsigned short u16;
typedef short s16;
typedef unsigned long long u64;
typedef __bf16 bf16_t;
typedef s16 s16x8 __attribute__((ext_vector_type(8)));
typedef float f32x4 __attribute__((ext_vector_type(4)));

__device__ __forceinline__ u16 bfbits(float f) {
    return __builtin_bit_cast(u16, (bf16_t)f);   // RNE f32->bf16, raw bits
}
// order-preserving bf16-bits -> u16 key (bigger float <=> bigger key)
__device__ __forceinline__ u16 map16(u16 b) {
    return (b & 0x8000u) ? (u16)~b : (u16)(b | 0x8000u);
}
__device__ __forceinline__ float unmap16(u32 m) {
    u16 b = (m & 0x8000u) ? (u16)(m & 0x7FFFu) : (u16)~(u16)m;
    return __uint_as_float(((u32)b) << 16);
}

__device__ __forceinline__ void gload16(const void* g, void* l) {
    __builtin_amdgcn_global_load_lds(
        (const __attribute__((address_space(1))) u32*)g,
        (__attribute__((address_space(3))) u32*)l, 16, 0, 0);
}

// ---------------- fp32 -> bf16 (both inputs, one launch) ----------------
__global__ __launch_bounds__(256) void cvt_bf16(const float* __restrict__ in0,
                                                const float* __restrict__ in1,
                                                u16* __restrict__ out0,
                                                u16* __restrict__ out1) {
    int b = blockIdx.x;
    const float* in = (b < 2048) ? in0 : in1;
    u16* out = (b < 2048) ? out0 : out1;
    int i = ((b & 2047) * 256 + threadIdx.x) * 4;
    float4 v = *(const float4*)(in + i);
    ushort4 o;
    o.x = bfbits(v.x); o.y = bfbits(v.y); o.z = bfbits(v.z); o.w = bfbits(v.w);
    *(ushort4*)(out + i) = o;
}

// ---------------- GEMM: keys = map16(bf16(Q @ K^T)) ----------------
// 128x128 tile, BK=64, 4 waves (2x2), wave = 64x64 via 4x4 frags of 16x16x32.
// Staging via global_load_lds dwordx4 with source-side chunk swizzle (rule #21).
// Diagonal tiles write the rank sentinel key 0 at (r,r).
__global__ __launch_bounds__(256) void gemm_keys(const u16* __restrict__ Qb,
                                                 const u16* __restrict__ Kb,
                                                 u16* __restrict__ Cp) {
    constexpr int BK = 64;
    __shared__ __align__(16) char smem[128 * 132 * 2];   // 33792 B (union)
    u16* sA = (u16*)smem;                    // [128][64] bf16
    u16* sB = (u16*)(smem + 128 * BK * 2);   // [128][64]
    u16* sC = (u16*)smem;                    // [128][132] epilogue transpose

    const int tid  = threadIdx.x;
    const int lane = tid & 63;
    const int wid  = tid >> 6;
    const int wr = wid >> 1, wc = wid & 1;
    const int bm = blockIdx.y * 128;
    const int bn = blockIdx.x * 128;
    const int kg = lane >> 4;
    const int fr = lane & 15;

    // staging: segment = 8 rows x 128B; lane l -> row seg*8 + (l>>3),
    // LDS chunk jp = l&7 holds source chunk j = jp ^ (row&7).
    const int srr = lane >> 3;
    const int srj = (lane & 7) ^ srr;

    f32x4 acc[4][4] = {};

    for (int k0 = 0; k0 < NDIM; k0 += BK) {
        __syncthreads();
#pragma unroll
        for (int s = 0; s < 4; ++s) {
            int seg = wid * 4 + s;                // 0..15
            int row = seg * 8 + srr;
            gload16(Qb + (size_t)(bm + row) * NDIM + k0 + srj * 8, &sA[seg * 512]);
            gload16(Kb + (size_t)(bn + row) * NDIM + k0 + srj * 8, &sB[seg * 512]);
        }
        __syncthreads();

#pragma unroll
        for (int kk = 0; kk < 2; ++kk) {
            s16x8 af[4], bfv[4];
#pragma unroll
            for (int m = 0; m < 4; ++m) {
                int row = wr * 64 + m * 16 + fr;
                int jp = (kk * 4 + kg) ^ (fr & 7);
                af[m] = *(const s16x8*)(&sA[row * BK + jp * 8]);
            }
#pragma unroll
            for (int n = 0; n < 4; ++n) {
                int row = wc * 64 + n * 16 + fr;
                int jp = (kk * 4 + kg) ^ (fr & 7);
                bfv[n] = *(const s16x8*)(&sB[row * BK + jp * 8]);
            }
#pragma unroll
            for (int m = 0; m < 4; ++m)
#pragma unroll
                for (int n = 0; n < 4; ++n)
                    acc[m][n] = __builtin_amdgcn_mfma_f32_16x16x32_bf16(
                        af[m], bfv[n], acc[m][n], 0, 0, 0);
        }
    }

    __syncthreads();   // done reading sA/sB; reuse LDS as sC
#pragma unroll
    for (int m = 0; m < 4; ++m)
#pragma unroll
        for (int n = 0; n < 4; ++n)
#pragma unroll
            for (int jj = 0; jj < 4; ++jj) {
                int r = wr * 64 + m * 16 + kg * 4 + jj;   // C/D: row = (lane>>4)*4+reg
                int c = wc * 64 + n * 16 + fr;            //      col = lane&15
                sC[r * 132 + c] = map16(bfbits(acc[m][n][jj]));
            }
    __syncthreads();
    if (bm == bn) {                      // diagonal tile: sentinel key 0 at (r,r)
        if (tid < 128) sC[tid * 132 + tid] = 0;
        __syncthreads();
    }
#pragma unroll
    for (int it = 0; it < 8; ++it) {
        int c = it * 256 + tid;                   // 16B chunk index, 0..2047
        int row = c >> 4, col8 = (c & 15) * 8;
        *(uint4*)(&Cp[(size_t)(bm + row) * NROW + bn + col8]) =
            *(const uint4*)(&sC[row * 132 + col8]);
    }
}

// ---------------- per-row rank select + LSE, LDS-resident keys ----------------
__global__ __launch_bounds__(256) void rank_lse(const u16* __restrict__ Cp,
                                                const float* __restrict__ fq,
                                                const float* __restrict__ fk,
                                                float* __restrict__ loss) {
    const int row = blockIdx.x;
    const int t = threadIdx.x;
    const int w = t >> 6;
    __shared__ u32 skey[4096];        // 16 KB: 8192 u16 keys, packed pairs
    __shared__ u32 wred[2][4];
    __shared__ float warr[4];
    __shared__ float wsum[4];
    __shared__ u32 wcnt[4][3];

    // stage the row into LDS (packed), 16B per thread per step
    const uint4* rowp = (const uint4*)(Cp + (size_t)row * NROW);
#pragma unroll
    for (int i = 0; i < 4; ++i)
        *(uint4*)&skey[(i * 256 + t) * 4] = rowp[i * 256 + t];

    // exact fp32 l_pos
    float p = fq[(size_t)row * NDIM + t] * fk[(size_t)row * NDIM + t];
#pragma unroll
    for (int o = 32; o; o >>= 1) p += __shfl_down(p, o);
    if ((t & 63) == 0) warr[w] = p;
    __syncthreads();
    const float lp = (warr[0] + warr[1]) + (warr[2] + warr[3]);

    // ballot bisection for rank K_BOT (A) and rank K_TOP-1 (B);
    // keys re-read from LDS each iteration (4x ds_read_b128, conflict-free)
    u32 loA = 0, hiA = 65535, loB = 0, hiB = 65535;
#pragma unroll 1
    for (int it = 0; it < 16; ++it) {
        const u32 mA = (loA + hiA) >> 1;
        const u32 mB = (loB + hiB) >> 1;
        const bool actA = loA < hiA;
        const bool actB = loB < hiB;
        const bool share = actA && actB && (mA == mB);
        u32 cA = 0, cB = 0;
#pragma unroll
        for (int i = 0; i < 4; ++i) {
            uint4 v = *(const uint4*)&skey[(i * 256 + t) * 4];
            u32 xs[4] = {v.x, v.y, v.z, v.w};
#pragma unroll
            for (int q = 0; q < 4; ++q) {
                u32 lo = xs[q] & 0xFFFFu, hi = xs[q] >> 16;
                if (actA) {
                    cA += (u32)__popcll(__ballot(lo > mA));
                    cA += (u32)__popcll(__ballot(hi > mA));
                }
                if (actB && !share) {
                    cB += (u32)__popcll(__ballot(lo > mB));
                    cB += (u32)__popcll(__ballot(hi > mB));
                }
            }
        }
        if (share) cB = cA;
        if ((t & 63) == 0) wred[it & 1][w] = (cA << 16) | cB;
        __syncthreads();
        const u32 s = wred[it & 1][0] + wred[it & 1][1]
                    + wred[it & 1][2] + wred[it & 1][3];
        if (actA) {
            const u32 CA = s >> 16;
            if (CA <= (u32)K_BOT) hiA = mA; else loA = mA + 1;
        }
        if (actB) {
            const u32 CB = s & 0xFFFFu;
            if (CB <= (u32)(K_TOP - 1)) hiB = mB; else loB = mB + 1;
        }
        if (loA >= hiA && loB >= hiB) break;   // uniform across block
    }
    const u32 ua = loA, ub = loB;

    // tie-exact window sum + LSE (one more LDS sweep)
    const float a  = unmap16(ua);
    const float bv = unmap16(ub);
    const float m_ = fmaxf(fmaxf(lp, a), -10.0f) * INV_T;

    u32 cga = 0, cea = 0, cgb = 0;
    float sm = 0.f;
#pragma unroll
    for (int i = 0; i < 4; ++i) {
        uint4 v = *(const uint4*)&skey[(i * 256 + t) * 4];
        u32 xs[4] = {v.x, v.y, v.z, v.w};
#pragma unroll
        for (int q = 0; q < 4; ++q) {
#pragma unroll
            for (int h = 0; h < 2; ++h) {
                u32 u = h ? (xs[q] >> 16) : (xs[q] & 0xFFFFu);
                cga += (u32)__popcll(__ballot(u > ua));
                cea += (u32)__popcll(__ballot(u == ua));
                cgb += (u32)__popcll(__ballot(u > ub));
                if (u < ua && u > ub) sm += __expf(unmap16(u) * INV_T - m_);
            }
        }
    }
#pragma unroll
    for (int o = 32; o; o >>= 1) sm += __shfl_down(sm, o);
    if ((t & 63) == 0) {
        wsum[w] = sm;
        wcnt[w][0] = cga; wcnt[w][1] = cea; wcnt[w][2] = cgb;
    }
    __syncthreads();
    if (t == 0) {
        float S = (wsum[0] + wsum[1]) + (wsum[2] + wsum[3]);
        u32 Ga = wcnt[0][0] + wcnt[1][0] + wcnt[2][0] + wcnt[3][0];
        u32 Ea = wcnt[0][1] + wcnt[1][1] + wcnt[2][1] + wcnt[3][1];
        u32 Gb = wcnt[0][2] + wcnt[1][2] + wcnt[2][2] + wcnt[3][2];
        float expA = __expf(a * INV_T - m_);
        float tot;
        if (ua == ub) {
            tot = (float)N_SEL * expA;
        } else {
            float expB = __expf(bv * INV_T - m_);
            tot = S + (float)(int)(Ga + Ea - (u32)K_BOT) * expA
                    + (float)(int)((u32)K_TOP - Gb) * expB;
        }
        tot += __expf(lp * INV_T - m_) + (float)N_UNSEL * __expf(-10.0f * INV_T - m_);
        loss[row] = m_ + __logf(tot) - lp * INV_T;
    }
}

// ---------------- host ----------------
extern "C" void kernel_launch(void* const* d_in, const int* in_sizes, int n_in,
                              void* d_out, int out_size, void* d_ws, size_t ws_size,
                              hipStream_t stream) {
    const float* fq = (const float*)d_in[0];
    const float* fk = (const float*)d_in[1];
    float* out = (float*)d_out;

    char* ws = (char*)d_ws;
    u16* keys = (u16*)ws;                                  // 128 MiB
    u16* qb = (u16*)(ws + (size_t)NROW * NROW * 2);        // 4 MiB
    u16* kb = qb + (size_t)NROW * NDIM;                    // 4 MiB

    cvt_bf16<<<4096, 256, 0, stream>>>(fq, fk, qb, kb);
    gemm_keys<<<dim3(NROW / 128, NROW / 128), 256, 0, stream>>>(qb, kb, keys);
    rank_lse<<<NROW, 256, 0, stream>>>(keys, fq, fk, out);
}

// Round 7
// 159.631 us; speedup vs baseline: 1.8997x; 1.8997x over previous
//
#include <hip/hip_runtime.h>
#include <hip/hip_bf16.h>

#define NROW 8192
#define NDIM 256
#define INV_T (1.0f / 0.07f)
#define K_BOT 819      // first selected descending rank
#define K_TOP 4095     // one past last selected rank
#define N_SEL 3276
#define N_UNSEL 4916   // 8192 - N_SEL (includes diagonal at -10)
#define NBIN 1024
#define CAPC 1024

typedef unsigned int u32;
typedef unsigned short u16;
typedef short s16;
typedef unsigned long long u64;
typedef __bf16 bf16_t;
typedef s16 s16x8 __attribute__((ext_vector_type(8)));
typedef float f32x4 __attribute__((ext_vector_type(4)));

__device__ __forceinline__ u16 bfbits(float f) {
    return __builtin_bit_cast(u16, (bf16_t)f);   // RNE f32->bf16, raw bits
}
// order-preserving bf16-bits -> u16 key (bigger float <=> bigger key)
__device__ __forceinline__ u16 map16(u16 b) {
    return (b & 0x8000u) ? (u16)~b : (u16)(b | 0x8000u);
}
__device__ __forceinline__ float unmap16(u32 m) {
    u16 b = (m & 0x8000u) ? (u16)(m & 0x7FFFu) : (u16)~(u16)m;
    return __uint_as_float(((u32)b) << 16);
}
// monotone linear value->bin map; sentinel key 0 -> NaN -> cvt 0 -> bin 0
__device__ __forceinline__ int binOf(u32 m) {
    float f = unmap16(m);
    int i = (int)((f + 90.0f) * (1024.0f / 180.0f));
    return min(max(i, 0), NBIN - 1);
}

__device__ __forceinline__ void gload16(const void* g, void* l) {
    __builtin_amdgcn_global_load_lds(
        (const __attribute__((address_space(1))) u32*)g,
        (__attribute__((address_space(3))) u32*)l, 16, 0, 0);
}

// ---------------- fp32 -> bf16 (both inputs, one launch) ----------------
__global__ __launch_bounds__(256) void cvt_bf16(const float* __restrict__ in0,
                                                const float* __restrict__ in1,
                                                u16* __restrict__ out0,
                                                u16* __restrict__ out1) {
    int b = blockIdx.x;
    const float* in = (b < 2048) ? in0 : in1;
    u16* out = (b < 2048) ? out0 : out1;
    int i = ((b & 2047) * 256 + threadIdx.x) * 4;
    float4 v = *(const float4*)(in + i);
    ushort4 o;
    o.x = bfbits(v.x); o.y = bfbits(v.y); o.z = bfbits(v.z); o.w = bfbits(v.w);
    *(ushort4*)(out + i) = o;
}

// ---------------- GEMM: keys = map16(bf16(Q @ K^T)) ----------------
__global__ __launch_bounds__(256) void gemm_keys(const u16* __restrict__ Qb,
                                                 const u16* __restrict__ Kb,
                                                 u16* __restrict__ Cp) {
    constexpr int BK = 64;
    __shared__ __align__(16) char smem[128 * 132 * 2];
    u16* sA = (u16*)smem;
    u16* sB = (u16*)(smem + 128 * BK * 2);
    u16* sC = (u16*)smem;

    const int tid  = threadIdx.x;
    const int lane = tid & 63;
    const int wid  = tid >> 6;
    const int wr = wid >> 1, wc = wid & 1;
    const int bm = blockIdx.y * 128;
    const int bn = blockIdx.x * 128;
    const int kg = lane >> 4;
    const int fr = lane & 15;
    const int srr = lane >> 3;
    const int srj = (lane & 7) ^ srr;

    f32x4 acc[4][4] = {};

    for (int k0 = 0; k0 < NDIM; k0 += BK) {
        __syncthreads();
#pragma unroll
        for (int s = 0; s < 4; ++s) {
            int seg = wid * 4 + s;
            int row = seg * 8 + srr;
            gload16(Qb + (size_t)(bm + row) * NDIM + k0 + srj * 8, &sA[seg * 512]);
            gload16(Kb + (size_t)(bn + row) * NDIM + k0 + srj * 8, &sB[seg * 512]);
        }
        __syncthreads();

#pragma unroll
        for (int kk = 0; kk < 2; ++kk) {
            s16x8 af[4], bfv[4];
#pragma unroll
            for (int m = 0; m < 4; ++m) {
                int row = wr * 64 + m * 16 + fr;
                int jp = (kk * 4 + kg) ^ (fr & 7);
                af[m] = *(const s16x8*)(&sA[row * BK + jp * 8]);
            }
#pragma unroll
            for (int n = 0; n < 4; ++n) {
                int row = wc * 64 + n * 16 + fr;
                int jp = (kk * 4 + kg) ^ (fr & 7);
                bfv[n] = *(const s16x8*)(&sB[row * BK + jp * 8]);
            }
#pragma unroll
            for (int m = 0; m < 4; ++m)
#pragma unroll
                for (int n = 0; n < 4; ++n)
                    acc[m][n] = __builtin_amdgcn_mfma_f32_16x16x32_bf16(
                        af[m], bfv[n], acc[m][n], 0, 0, 0);
        }
    }

    __syncthreads();
#pragma unroll
    for (int m = 0; m < 4; ++m)
#pragma unroll
        for (int n = 0; n < 4; ++n)
#pragma unroll
            for (int jj = 0; jj < 4; ++jj) {
                int r = wr * 64 + m * 16 + kg * 4 + jj;
                int c = wc * 64 + n * 16 + fr;
                sC[r * 132 + c] = map16(bfbits(acc[m][n][jj]));
            }
    __syncthreads();
    if (bm == bn) {
        if (tid < 128) sC[tid * 132 + tid] = 0;   // diagonal sentinel (unique min)
        __syncthreads();
    }
#pragma unroll
    for (int it = 0; it < 8; ++it) {
        int c = it * 256 + tid;
        int row = c >> 4, col8 = (c & 15) * 8;
        *(uint4*)(&Cp[(size_t)(bm + row) * NROW + bn + col8]) =
            *(const uint4*)(&sC[row * 132 + col8]);
    }
}

// ---------------- wave helpers ----------------
__device__ __forceinline__ u32 wave_sum_u32(u32 x) {
#pragma unroll
    for (int o = 32; o; o >>= 1) x += __shfl_down(x, o);
    return __shfl(x, 0);
}

// exact u16-bisect over a compact LDS list: value at descending rank `rank`
__device__ u32 bisect_list(const u16* lst, u32 n, u32 rank, int lane) {
    const u32 nE = (n + 63) >> 6;          // wave-uniform
    u32 lo = 0, hi = 65535;
    while (lo < hi) {
        u32 mid = (lo + hi) >> 1;
        u32 c = 0;
        for (u32 i = 0; i < nE; ++i) {
            u32 idx = (u32)lane + i * 64;
            u32 k = (idx < n) ? (u32)lst[idx] : 0u;
            c += (u32)__popcll(__ballot(k > mid));
        }
        if (c <= rank) hi = mid; else lo = mid + 1;
    }
    return lo;
}

__device__ void count_list(const u16* lst, u32 n, u32 x, int lane,
                           u32* gt, u32* eq) {
    const u32 nE = (n + 63) >> 6;
    u32 g = 0, e = 0;
    for (u32 i = 0; i < nE; ++i) {
        u32 idx = (u32)lane + i * 64;
        bool v = idx < n;
        u32 k = v ? (u32)lst[idx] : 0u;
        g += (u32)__popcll(__ballot(v && k > x));
        e += (u32)__popcll(__ballot(v && k == x));
    }
    *gt = g; *eq = e;
}

__device__ float sumwin_list(const u16* lst, u32 n, u32 ua, u32 ub,
                             float m_, int lane) {
    const u32 nE = (n + 63) >> 6;
    float s = 0.f;
    for (u32 i = 0; i < nE; ++i) {
        u32 idx = (u32)lane + i * 64;
        if (idx < n) {
            u32 k = lst[idx];
            if (k > ub && k < ua) s += __expf(unmap16(k) * INV_T - m_);
        }
    }
    return s;   // per-lane partial
}

// full-row bisect via global re-sweeps (pathological fallback only)
__device__ u32 bisect_row(const uint4* rp, u32 rank, int lane) {
    u32 lo = 0, hi = 65535;
    while (lo < hi) {
        u32 mid = (lo + hi) >> 1;
        u32 pc = 0;
        for (int i = 0; i < 16; ++i) {
            uint4 v = rp[i * 64 + lane];
            pc += (u32)((v.x & 0xFFFFu) > mid) + (u32)((v.x >> 16) > mid)
                + (u32)((v.y & 0xFFFFu) > mid) + (u32)((v.y >> 16) > mid)
                + (u32)((v.z & 0xFFFFu) > mid) + (u32)((v.z >> 16) > mid)
                + (u32)((v.w & 0xFFFFu) > mid) + (u32)((v.w >> 16) > mid);
        }
        u32 c = wave_sum_u32(pc);
        if (c <= rank) hi = mid; else lo = mid + 1;
    }
    return lo;
}

// ---------------- per-row rank select + LSE: 1 wave/row, 0 barriers --------
__global__ __launch_bounds__(256) void rank_lse(const u16* __restrict__ Cp,
                                                const float* __restrict__ fq,
                                                const float* __restrict__ fk,
                                                float* __restrict__ loss) {
    __shared__ u32 hist_s[4][NBIN];        // 16 KB (per-wave private)
    __shared__ u16 cand_s[4][2 * CAPC];    // 16 KB (per-wave A|B lists)
    __shared__ u32 cnt_s[4][2];

    const int t = threadIdx.x;
    const int w = t >> 6;
    const int lane = t & 63;
    const int row = blockIdx.x * 4 + w;

    u32* hist  = hist_s[w];
    u16* candA = cand_s[w];
    u16* candB = cand_s[w] + CAPC;
    u32* cnt   = cnt_s[w];

    const uint4* rp = (const uint4*)(Cp + (size_t)row * NROW);

    // zero hist + counters (wave-private; DS pipe is in-order per wave)
    {
        const uint4 z = make_uint4(0, 0, 0, 0);
#pragma unroll
        for (int i = 0; i < 4; ++i)
            *(uint4*)&hist[lane * 16 + i * 4] = z;
        if (lane < 2) cnt[lane] = 0;
    }

    // exact fp32 l_pos
    float lp;
    {
        float4 q4 = *(const float4*)(fq + (size_t)row * NDIM + lane * 4);
        float4 k4 = *(const float4*)(fk + (size_t)row * NDIM + lane * 4);
        float p = q4.x * k4.x + q4.y * k4.y + q4.z * k4.z + q4.w * k4.w;
#pragma unroll
        for (int o = 32; o; o >>= 1) p += __shfl_down(p, o);
        lp = __shfl(p, 0);
    }

    // ---- pass 1: linear-bin histogram ----
#pragma unroll 4
    for (int i = 0; i < 16; ++i) {
        uint4 v = rp[i * 64 + lane];
        u32 ks[8] = { v.x & 0xFFFFu, v.x >> 16, v.y & 0xFFFFu, v.y >> 16,
                      v.z & 0xFFFFu, v.z >> 16, v.w & 0xFFFFu, v.w >> 16 };
#pragma unroll
        for (int q = 0; q < 8; ++q)
            atomicAdd(&hist[binOf(ks[q])], 1u);
    }

    // ---- wave-local suffix scan; locate boundary bins exactly ----
    u32 h[16], Wa[16];
#pragma unroll
    for (int i = 0; i < 4; ++i) {
        uint4 hv = *(const uint4*)&hist[lane * 16 + i * 4];
        h[i * 4 + 0] = hv.x; h[i * 4 + 1] = hv.y;
        h[i * 4 + 2] = hv.z; h[i * 4 + 3] = hv.w;
    }
    Wa[15] = 0;
#pragma unroll
    for (int j = 14; j >= 0; --j) Wa[j] = Wa[j + 1] + h[j + 1];
    u32 P = Wa[0] + h[0];
    u32 s = P;
#pragma unroll
    for (int o = 1; o < 64; o <<= 1) {
        u32 vv = __shfl_down(s, o);
        if (lane + o < 64) s += vv;
    }
    const u32 Tex = s - P;     // keys in bins owned by higher lanes

    u32 fA = 0, pkA = 0, fB = 0, pkB = 0;
#pragma unroll
    for (int j = 0; j < 16; ++j) {
        u32 T = Tex + Wa[j];          // keys in bins strictly above this bin
        u32 e = T + h[j];
        if ((u32)K_BOT >= T && (u32)K_BOT < e)
            { fA = 1; pkA = ((u32)(lane * 16 + j) << 13) | ((u32)K_BOT - T); }
        if ((u32)(K_TOP - 1) >= T && (u32)(K_TOP - 1) < e)
            { fB = 1; pkB = ((u32)(lane * 16 + j) << 13) | ((u32)(K_TOP - 1) - T); }
    }
    {
        u64 mA = __ballot(fA != 0);
        pkA = __shfl(pkA, __ffsll((unsigned long long)mA) - 1);
        u64 mB = __ballot(fB != 0);
        pkB = __shfl(pkB, __ffsll((unsigned long long)mB) - 1);
    }
    const u32 binA = pkA >> 13, remA = pkA & 8191u;
    const u32 binB = pkB >> 13, remB = pkB & 8191u;
    const u32 TA = (u32)K_BOT - remA;
    const u32 TB = (u32)(K_TOP - 1) - remB;
    const u32 hA = hist[binA];
    const u32 hB = hist[binB];
    const bool same = (binA == binB);

    u32 ua, ub, Ga, Ea, Gb;
    float m_, smLane;

    if (hA <= CAPC && hB <= CAPC) {
        // ---- fast path: pass 2 = mid-bin exp + boundary-bin compaction ----
        const float aUp = (float)(binA + 1) * (180.0f / 1024.0f) - 90.0f;
        m_ = fmaxf(fmaxf(lp, aUp), -10.0f) * INV_T;   // >= true window max
        float sm = 0.f;
#pragma unroll 4
        for (int i = 0; i < 16; ++i) {
            uint4 v = rp[i * 64 + lane];
            u32 ks[8] = { v.x & 0xFFFFu, v.x >> 16, v.y & 0xFFFFu, v.y >> 16,
                          v.z & 0xFFFFu, v.z >> 16, v.w & 0xFFFFu, v.w >> 16 };
#pragma unroll
            for (int q = 0; q < 8; ++q) {
                u32 key = ks[q];
                u32 b = (u32)binOf(key);
                if (b == binA) {
                    u32 ix = atomicAdd(&cnt[0], 1u);
                    candA[ix] = (u16)key;
                } else if (!same && b == binB) {
                    u32 ix = atomicAdd(&cnt[1], 1u);
                    candB[ix] = (u16)key;
                } else if (b > binB && b < binA) {
                    sm += __expf(unmap16(key) * INV_T - m_);
                }
            }
        }
        const u32 nA = hA;
        const u32 nB = same ? hA : hB;
        const u16* lB = same ? candA : candB;
        ua = bisect_list(candA, nA, remA, lane);
        ub = bisect_list(lB, nB, remB, lane);
        u32 gA, eA, gB, eB;
        count_list(candA, nA, ua, lane, &gA, &eA);
        count_list(lB, nB, ub, lane, &gB, &eB);
        Ga = TA + gA; Ea = eA; Gb = TB + gB;
        sm += sumwin_list(candA, nA, ua, ub, m_, lane);
        if (!same) sm += sumwin_list(candB, nB, ua, ub, m_, lane);
        smLane = sm;
    } else {
        // ---- fallback: exact full-row bisect (pathological data only) ----
        ua = bisect_row(rp, (u32)K_BOT, lane);
        ub = bisect_row(rp, (u32)(K_TOP - 1), lane);
        m_ = fmaxf(fmaxf(lp, unmap16(ua)), -10.0f) * INV_T;
        u32 cga = 0, cea = 0, cgb = 0;
        float sm = 0.f;
        for (int i = 0; i < 16; ++i) {
            uint4 v = rp[i * 64 + lane];
            u32 ks[8] = { v.x & 0xFFFFu, v.x >> 16, v.y & 0xFFFFu, v.y >> 16,
                          v.z & 0xFFFFu, v.z >> 16, v.w & 0xFFFFu, v.w >> 16 };
#pragma unroll
            for (int q = 0; q < 8; ++q) {
                u32 u = ks[q];
                cga += (u > ua); cea += (u == ua); cgb += (u > ub);
                if (u > ub && u < ua) sm += __expf(unmap16(u) * INV_T - m_);
            }
        }
        Ga = wave_sum_u32(cga); Ea = wave_sum_u32(cea); Gb = wave_sum_u32(cgb);
        smLane = sm;
    }

    // wave-reduce the exp partials
    float smT = smLane;
#pragma unroll
    for (int o = 32; o; o >>= 1) smT += __shfl_down(smT, o);

    if (lane == 0) {
        float a = unmap16(ua), bv = unmap16(ub);
        float expA = __expf(a * INV_T - m_);
        float tot;
        if (ua == ub) {
            tot = (float)N_SEL * expA;
        } else {
            float expB = __expf(bv * INV_T - m_);
            tot = smT + (float)(int)(Ga + Ea - (u32)K_BOT) * expA
                      + (float)(int)((u32)K_TOP - Gb) * expB;
        }
        tot += __expf(lp * INV_T - m_) + (float)N_UNSEL * __expf(-10.0f * INV_T - m_);
        loss[row] = m_ + __logf(tot) - lp * INV_T;
    }
}

// ---------------- host ----------------
extern "C" void kernel_launch(void* const* d_in, const int* in_sizes, int n_in,
                              void* d_out, int out_size, void* d_ws, size_t ws_size,
                              hipStream_t stream) {
    const float* fq = (const float*)d_in[0];
    const float* fk = (const float*)d_in[1];
    float* out = (float*)d_out;

    char* ws = (char*)d_ws;
    u16* keys = (u16*)ws;                                  // 128 MiB
    u16* qb = (u16*)(ws + (size_t)NROW * NROW * 2);        // 4 MiB
    u16* kb = qb + (size_t)NROW * NDIM;                    // 4 MiB

    cvt_bf16<<<4096, 256, 0, stream>>>(fq, fk, qb, kb);
    gemm_keys<<<dim3(NROW / 128, NROW / 128), 256, 0, stream>>>(qb, kb, keys);
    rank_lse<<<NROW / 4, 256, 0, stream>>>(keys, fq, fk, out);
}

// Round 8
// 146.666 us; speedup vs baseline: 2.0676x; 1.0884x over previous
//
#include <hip/hip_runtime.h>
#include <hip/hip_bf16.h>

#define NROW 8192
#define NDIM 256
#define INV_T (1.0f / 0.07f)
#define K_BOT 819      // first selected descending rank
#define K_TOP 4095     // one past last selected rank
#define N_SEL 3276
#define N_UNSEL 4916   // 8192 - N_SEL (includes diagonal at -10)
#define NBIN 512
#define CAPC 448

typedef unsigned int u32;
typedef unsigned short u16;
typedef short s16;
typedef unsigned long long u64;
typedef __bf16 bf16_t;
typedef s16 s16x8 __attribute__((ext_vector_type(8)));
typedef float f32x4 __attribute__((ext_vector_type(4)));

__device__ __forceinline__ u16 bfbits(float f) {
    return __builtin_bit_cast(u16, (bf16_t)f);   // RNE f32->bf16, raw bits
}
// order-preserving bf16-bits -> u16 key (bigger float <=> bigger key)
__device__ __forceinline__ u16 map16(u16 b) {
    return (b & 0x8000u) ? (u16)~b : (u16)(b | 0x8000u);
}
__device__ __forceinline__ float unmap16(u32 m) {
    u16 b = (m & 0x8000u) ? (u16)(m & 0x7FFFu) : (u16)~(u16)m;
    return __uint_as_float(((u32)b) << 16);
}
// monotone linear value->bin map; sentinel key 0 -> NaN -> cvt 0 -> bin 0
__device__ __forceinline__ int binOf(u32 m) {
    float f = unmap16(m);
    int i = (int)((f + 90.0f) * ((float)NBIN / 180.0f));
    return min(max(i, 0), NBIN - 1);
}

__device__ __forceinline__ void gload16(const void* g, void* l) {
    __builtin_amdgcn_global_load_lds(
        (const __attribute__((address_space(1))) u32*)g,
        (__attribute__((address_space(3))) u32*)l, 16, 0, 0);
}

// ---------------- fp32 -> bf16 (both inputs, one launch) ----------------
__global__ __launch_bounds__(256) void cvt_bf16(const float* __restrict__ in0,
                                                const float* __restrict__ in1,
                                                u16* __restrict__ out0,
                                                u16* __restrict__ out1) {
    int b = blockIdx.x;
    const float* in = (b < 2048) ? in0 : in1;
    u16* out = (b < 2048) ? out0 : out1;
    int i = ((b & 2047) * 256 + threadIdx.x) * 4;
    float4 v = *(const float4*)(in + i);
    ushort4 o;
    o.x = bfbits(v.x); o.y = bfbits(v.y); o.z = bfbits(v.z); o.w = bfbits(v.w);
    *(ushort4*)(out + i) = o;
}

// ---------------- GEMM: keys = map16(bf16(Q @ K^T)) ----------------
__global__ __launch_bounds__(256) void gemm_keys(const u16* __restrict__ Qb,
                                                 const u16* __restrict__ Kb,
                                                 u16* __restrict__ Cp) {
    constexpr int BK = 64;
    __shared__ __align__(16) char smem[128 * 132 * 2];
    u16* sA = (u16*)smem;
    u16* sB = (u16*)(smem + 128 * BK * 2);
    u16* sC = (u16*)smem;

    const int tid  = threadIdx.x;
    const int lane = tid & 63;
    const int wid  = tid >> 6;
    const int wr = wid >> 1, wc = wid & 1;
    const int bm = blockIdx.y * 128;
    const int bn = blockIdx.x * 128;
    const int kg = lane >> 4;
    const int fr = lane & 15;
    const int srr = lane >> 3;
    const int srj = (lane & 7) ^ srr;

    f32x4 acc[4][4] = {};

    for (int k0 = 0; k0 < NDIM; k0 += BK) {
        __syncthreads();
#pragma unroll
        for (int s = 0; s < 4; ++s) {
            int seg = wid * 4 + s;
            int row = seg * 8 + srr;
            gload16(Qb + (size_t)(bm + row) * NDIM + k0 + srj * 8, &sA[seg * 512]);
            gload16(Kb + (size_t)(bn + row) * NDIM + k0 + srj * 8, &sB[seg * 512]);
        }
        __syncthreads();

#pragma unroll
        for (int kk = 0; kk < 2; ++kk) {
            s16x8 af[4], bfv[4];
#pragma unroll
            for (int m = 0; m < 4; ++m) {
                int row = wr * 64 + m * 16 + fr;
                int jp = (kk * 4 + kg) ^ (fr & 7);
                af[m] = *(const s16x8*)(&sA[row * BK + jp * 8]);
            }
#pragma unroll
            for (int n = 0; n < 4; ++n) {
                int row = wc * 64 + n * 16 + fr;
                int jp = (kk * 4 + kg) ^ (fr & 7);
                bfv[n] = *(const s16x8*)(&sB[row * BK + jp * 8]);
            }
#pragma unroll
            for (int m = 0; m < 4; ++m)
#pragma unroll
                for (int n = 0; n < 4; ++n)
                    acc[m][n] = __builtin_amdgcn_mfma_f32_16x16x32_bf16(
                        af[m], bfv[n], acc[m][n], 0, 0, 0);
        }
    }

    __syncthreads();
#pragma unroll
    for (int m = 0; m < 4; ++m)
#pragma unroll
        for (int n = 0; n < 4; ++n)
#pragma unroll
            for (int jj = 0; jj < 4; ++jj) {
                int r = wr * 64 + m * 16 + kg * 4 + jj;
                int c = wc * 64 + n * 16 + fr;
                sC[r * 132 + c] = map16(bfbits(acc[m][n][jj]));
            }
    __syncthreads();
    if (bm == bn) {
        if (tid < 128) sC[tid * 132 + tid] = 0;   // diagonal sentinel (unique min)
        __syncthreads();
    }
#pragma unroll
    for (int it = 0; it < 8; ++it) {
        int c = it * 256 + tid;
        int row = c >> 4, col8 = (c & 15) * 8;
        *(uint4*)(&Cp[(size_t)(bm + row) * NROW + bn + col8]) =
            *(const uint4*)(&sC[row * 132 + col8]);
    }
}

// ---------------- wave helpers ----------------
__device__ __forceinline__ u32 wave_sum_u32(u32 x) {
#pragma unroll
    for (int o = 32; o; o >>= 1) x += __shfl_down(x, o);
    return __shfl(x, 0);
}

// exact u16-bisect over a compact LDS list: value at descending rank `rank`
__device__ u32 bisect_list(const u16* lst, u32 n, u32 rank, int lane) {
    const u32 nE = (n + 63) >> 6;          // wave-uniform
    u32 lo = 0, hi = 65535;
    while (lo < hi) {
        u32 mid = (lo + hi) >> 1;
        u32 c = 0;
        for (u32 i = 0; i < nE; ++i) {
            u32 idx = (u32)lane + i * 64;
            u32 k = (idx < n) ? (u32)lst[idx] : 0u;
            c += (u32)__popcll(__ballot(k > mid));
        }
        if (c <= rank) hi = mid; else lo = mid + 1;
    }
    return lo;
}

__device__ void count_list(const u16* lst, u32 n, u32 x, int lane,
                           u32* gt, u32* eq) {
    const u32 nE = (n + 63) >> 6;
    u32 g = 0, e = 0;
    for (u32 i = 0; i < nE; ++i) {
        u32 idx = (u32)lane + i * 64;
        bool v = idx < n;
        u32 k = v ? (u32)lst[idx] : 0u;
        g += (u32)__popcll(__ballot(v && k > x));
        e += (u32)__popcll(__ballot(v && k == x));
    }
    *gt = g; *eq = e;
}

__device__ float sumwin_list(const u16* lst, u32 n, u32 ua, u32 ub,
                             float m_, int lane) {
    const u32 nE = (n + 63) >> 6;
    float s = 0.f;
    for (u32 i = 0; i < nE; ++i) {
        u32 idx = (u32)lane + i * 64;
        if (idx < n) {
            u32 k = lst[idx];
            if (k > ub && k < ua) s += __expf(unmap16(k) * INV_T - m_);
        }
    }
    return s;   // per-lane partial
}

// full-row bisect via global re-sweeps (pathological fallback only)
__device__ u32 bisect_row(const uint4* rp, u32 rank, int lane) {
    u32 lo = 0, hi = 65535;
    while (lo < hi) {
        u32 mid = (lo + hi) >> 1;
        u32 pc = 0;
        for (int i = 0; i < 16; ++i) {
            uint4 v = rp[i * 64 + lane];
            pc += (u32)((v.x & 0xFFFFu) > mid) + (u32)((v.x >> 16) > mid)
                + (u32)((v.y & 0xFFFFu) > mid) + (u32)((v.y >> 16) > mid)
                + (u32)((v.z & 0xFFFFu) > mid) + (u32)((v.z >> 16) > mid)
                + (u32)((v.w & 0xFFFFu) > mid) + (u32)((v.w >> 16) > mid);
        }
        u32 c = wave_sum_u32(pc);
        if (c <= rank) hi = mid; else lo = mid + 1;
    }
    return lo;
}

// ---------------- per-row rank select + LSE: 1 wave/row, 0 barriers --------
__global__ __launch_bounds__(256, 8) void rank_lse(const u16* __restrict__ Cp,
                                                   const float* __restrict__ fq,
                                                   const float* __restrict__ fk,
                                                   float* __restrict__ loss) {
    __shared__ u32 hist_s[4][NBIN];        // 8 KB (per-wave private)
    __shared__ u16 cand_s[4][2 * CAPC];    // 7 KB (per-wave A|B lists)
    __shared__ u32 cnt_s[4][2];

    const int t = threadIdx.x;
    const int w = t >> 6;
    const int lane = t & 63;
    const int row = blockIdx.x * 4 + w;

    u32* hist  = hist_s[w];
    u16* candA = cand_s[w];
    u16* candB = cand_s[w] + CAPC;
    u32* cnt   = cnt_s[w];

    const uint4* rp = (const uint4*)(Cp + (size_t)row * NROW);

    // zero hist + counters (wave-private; DS pipe is in-order per wave)
    {
        const uint4 z = make_uint4(0, 0, 0, 0);
        *(uint4*)&hist[lane * 8]     = z;
        *(uint4*)&hist[lane * 8 + 4] = z;
        if (lane < 2) cnt[lane] = 0;
    }

    // exact fp32 l_pos
    float lp;
    {
        float4 q4 = *(const float4*)(fq + (size_t)row * NDIM + lane * 4);
        float4 k4 = *(const float4*)(fk + (size_t)row * NDIM + lane * 4);
        float p = q4.x * k4.x + q4.y * k4.y + q4.z * k4.z + q4.w * k4.w;
#pragma unroll
        for (int o = 32; o; o >>= 1) p += __shfl_down(p, o);
        lp = __shfl(p, 0);
    }

    // ---- pass 1: linear-bin histogram ----
#pragma unroll 4
    for (int i = 0; i < 16; ++i) {
        uint4 v = rp[i * 64 + lane];
        u32 ks[8] = { v.x & 0xFFFFu, v.x >> 16, v.y & 0xFFFFu, v.y >> 16,
                      v.z & 0xFFFFu, v.z >> 16, v.w & 0xFFFFu, v.w >> 16 };
#pragma unroll
        for (int q = 0; q < 8; ++q)
            atomicAdd(&hist[binOf(ks[q])], 1u);
    }

    // ---- wave-local suffix scan (8 bins/lane); locate boundary bins ----
    u32 h[8], Wa[8];
    {
        uint4 h0 = *(const uint4*)&hist[lane * 8];
        uint4 h1 = *(const uint4*)&hist[lane * 8 + 4];
        h[0] = h0.x; h[1] = h0.y; h[2] = h0.z; h[3] = h0.w;
        h[4] = h1.x; h[5] = h1.y; h[6] = h1.z; h[7] = h1.w;
    }
    Wa[7] = 0;
#pragma unroll
    for (int j = 6; j >= 0; --j) Wa[j] = Wa[j + 1] + h[j + 1];
    u32 P = Wa[0] + h[0];
    u32 s = P;
#pragma unroll
    for (int o = 1; o < 64; o <<= 1) {
        u32 vv = __shfl_down(s, o);
        if (lane + o < 64) s += vv;
    }
    const u32 Tex = s - P;     // keys in bins owned by higher lanes

    u32 fA = 0, pkA = 0, fB = 0, pkB = 0;
#pragma unroll
    for (int j = 0; j < 8; ++j) {
        u32 T = Tex + Wa[j];          // keys in bins strictly above this bin
        u32 e = T + h[j];
        if ((u32)K_BOT >= T && (u32)K_BOT < e)
            { fA = 1; pkA = ((u32)(lane * 8 + j) << 13) | ((u32)K_BOT - T); }
        if ((u32)(K_TOP - 1) >= T && (u32)(K_TOP - 1) < e)
            { fB = 1; pkB = ((u32)(lane * 8 + j) << 13) | ((u32)(K_TOP - 1) - T); }
    }
    {
        u64 mA = __ballot(fA != 0);
        pkA = __shfl(pkA, __ffsll((unsigned long long)mA) - 1);
        u64 mB = __ballot(fB != 0);
        pkB = __shfl(pkB, __ffsll((unsigned long long)mB) - 1);
    }
    const u32 binA = pkA >> 13, remA = pkA & 8191u;
    const u32 binB = pkB >> 13, remB = pkB & 8191u;
    const u32 TA = (u32)K_BOT - remA;
    const u32 TB = (u32)(K_TOP - 1) - remB;
    const u32 hA = hist[binA];
    const u32 hB = hist[binB];
    const bool same = (binA == binB);

    u32 ua, ub, Ga, Ea, Gb;
    float m_, smLane;

    if (hA <= CAPC && hB <= CAPC) {
        // ---- fast path: pass 2 = mid-bin exp + boundary-bin compaction ----
        const float aUp = (float)(binA + 1) * (180.0f / (float)NBIN) - 90.0f;
        m_ = fmaxf(fmaxf(lp, aUp), -10.0f) * INV_T;   // >= true window max
        float sm = 0.f;
#pragma unroll 4
        for (int i = 0; i < 16; ++i) {
            uint4 v = rp[i * 64 + lane];
            u32 ks[8] = { v.x & 0xFFFFu, v.x >> 16, v.y & 0xFFFFu, v.y >> 16,
                          v.z & 0xFFFFu, v.z >> 16, v.w & 0xFFFFu, v.w >> 16 };
#pragma unroll
            for (int q = 0; q < 8; ++q) {
                u32 key = ks[q];
                u32 b = (u32)binOf(key);
                if (b == binA) {
                    u32 ix = atomicAdd(&cnt[0], 1u);
                    candA[ix] = (u16)key;
                } else if (!same && b == binB) {
                    u32 ix = atomicAdd(&cnt[1], 1u);
                    candB[ix] = (u16)key;
                } else if (b > binB && b < binA) {
                    sm += __expf(unmap16(key) * INV_T - m_);
                }
            }
        }
        const u32 nA = hA;
        const u32 nB = same ? hA : hB;
        const u16* lB = same ? candA : candB;
        ua = bisect_list(candA, nA, remA, lane);
        ub = bisect_list(lB, nB, remB, lane);
        u32 gA, eA, gB, eB;
        count_list(candA, nA, ua, lane, &gA, &eA);
        count_list(lB, nB, ub, lane, &gB, &eB);
        Ga = TA + gA; Ea = eA; Gb = TB + gB;
        sm += sumwin_list(candA, nA, ua, ub, m_, lane);
        if (!same) sm += sumwin_list(candB, nB, ua, ub, m_, lane);
        smLane = sm;
    } else {
        // ---- fallback: exact full-row bisect (pathological data only) ----
        ua = bisect_row(rp, (u32)K_BOT, lane);
        ub = bisect_row(rp, (u32)(K_TOP - 1), lane);
        m_ = fmaxf(fmaxf(lp, unmap16(ua)), -10.0f) * INV_T;
        u32 cga = 0, cea = 0, cgb = 0;
        float sm = 0.f;
        for (int i = 0; i < 16; ++i) {
            uint4 v = rp[i * 64 + lane];
            u32 ks[8] = { v.x & 0xFFFFu, v.x >> 16, v.y & 0xFFFFu, v.y >> 16,
                          v.z & 0xFFFFu, v.z >> 16, v.w & 0xFFFFu, v.w >> 16 };
#pragma unroll
            for (int q = 0; q < 8; ++q) {
                u32 u = ks[q];
                cga += (u > ua); cea += (u == ua); cgb += (u > ub);
                if (u > ub && u < ua) sm += __expf(unmap16(u) * INV_T - m_);
            }
        }
        Ga = wave_sum_u32(cga); Ea = wave_sum_u32(cea); Gb = wave_sum_u32(cgb);
        smLane = sm;
    }

    // wave-reduce the exp partials
    float smT = smLane;
#pragma unroll
    for (int o = 32; o; o >>= 1) smT += __shfl_down(smT, o);

    if (lane == 0) {
        float a = unmap16(ua), bv = unmap16(ub);
        float expA = __expf(a * INV_T - m_);
        float tot;
        if (ua == ub) {
            tot = (float)N_SEL * expA;
        } else {
            float expB = __expf(bv * INV_T - m_);
            tot = smT + (float)(int)(Ga + Ea - (u32)K_BOT) * expA
                      + (float)(int)((u32)K_TOP - Gb) * expB;
        }
        tot += __expf(lp * INV_T - m_) + (float)N_UNSEL * __expf(-10.0f * INV_T - m_);
        loss[row] = m_ + __logf(tot) - lp * INV_T;
    }
}

// ---------------- host ----------------
extern "C" void kernel_launch(void* const* d_in, const int* in_sizes, int n_in,
                              void* d_out, int out_size, void* d_ws, size_t ws_size,
                              hipStream_t stream) {
    const float* fq = (const float*)d_in[0];
    const float* fk = (const float*)d_in[1];
    float* out = (float*)d_out;

    char* ws = (char*)d_ws;
    u16* keys = (u16*)ws;                                  // 128 MiB
    u16* qb = (u16*)(ws + (size_t)NROW * NROW * 2);        // 4 MiB
    u16* kb = qb + (size_t)NROW * NDIM;                    // 4 MiB

    cvt_bf16<<<4096, 256, 0, stream>>>(fq, fk, qb, kb);
    gemm_keys<<<dim3(NROW / 128, NROW / 128), 256, 0, stream>>>(qb, kb, keys);
    rank_lse<<<NROW / 4, 256, 0, stream>>>(keys, fq, fk, out);
}